// Round 11
// baseline (131.534 us; speedup 1.0000x reference)
//
#include <hip/hip_runtime.h>

#define TSTEPS 128
#define NBATCH 2048
#define DIN    32
#define INV_PI 0.31830988618379067f

// ---- quad-scoped DPP permute (acts within each group of 4 lanes) ----
template <int CTRL>
__device__ __forceinline__ float qperm(float v) {
    return __int_as_float(
        __builtin_amdgcn_mov_dpp(__float_as_int(v), CTRL, 0xF, 0xF, true));
}
// quad_perm ctrl: sel3<<6|sel2<<4|sel1<<2|sel0.
//  0x90 = [0,0,1,2] shift-up-1 ; 0x44 = [0,1,0,1] shift-up-2
//  0x00/0x55/0xAA/0xFF = broadcast quad-lane 0/1/2/3

// ============================ Fused single kernel ============================
// Grid 512 x 64 (1 wave). Block owns batches B0..B0+3 for all 128 timesteps.
//
// Phase 1 (all 64 lanes): x-projection into LDS.
//   Xp[row][i] (float4, row = t*4+bl) = (pf,pi,pu,po) for hidden i =
//   (1/pi)*(b_g[i] + x[t,B0+bl,:] . W_g[i,0:32]),  gate order f,i,u,o.
// Phase 2 (lanes 0..15): recurrence. lane = bl*4 + i  (quad = one batch).
//   ALL per-gate math in-lane; c_i lives on lane i. Cross-lane ops per step:
//   prefix-product (2 DPP deep) + h-broadcast (4 one-hop DPP, depth 1).
extern "C" __global__ void __launch_bounds__(64)
qlstm_one(const float* __restrict__ x,
          const float* __restrict__ Wf, const float* __restrict__ bfp,
          const float* __restrict__ Wi, const float* __restrict__ bip,
          const float* __restrict__ Wu, const float* __restrict__ bup,
          const float* __restrict__ Wo, const float* __restrict__ bop,
          float* __restrict__ out)
{
    __shared__ float4 WL[16 * 8];     // 2 KB, row rr = i*4+g
    __shared__ float  biasS[16];
    __shared__ float4 Xp[512 * 4];    // 32 KB, [row=t*4+bl][i]

    const int l  = threadIdx.x;
    const int B0 = blockIdx.x * 4;

    // ---- stage weights (pre-scaled 1/pi), i-major ----
    float* WLf = (float*)WL;
    for (int idx = l; idx < 512; idx += 64) {
        int rr = idx >> 5, k = idx & 31;
        int i = rr >> 2, g = rr & 3;
        const float* W = (g == 0) ? Wf : (g == 1) ? Wi : (g == 2) ? Wu : Wo;
        WLf[rr * 32 + k] = W[i * 36 + k] * INV_PI;
    }
    if (l < 16) {
        int i = l >> 2, g = l & 3;
        const float* bp = (g == 0) ? bfp : (g == 1) ? bip : (g == 2) ? bup : bop;
        biasS[l] = bp[i] * INV_PI;
    }
    __syncthreads();

    // ---- phase 1: 8 rows per lane (rows m*64+l are wave-contiguous) ----
#pragma unroll
    for (int m = 0; m < 8; ++m) {
        const int R = m * 64 + l;              // 0..511
        const int t = R >> 2, b = R & 3;
        const float4* xv = reinterpret_cast<const float4*>(
            x + ((size_t)t * NBATCH + (size_t)(B0 + b)) * DIN);
        float4 a[8];
#pragma unroll
        for (int k = 0; k < 8; ++k) a[k] = xv[k];
#pragma unroll
        for (int ii = 0; ii < 4; ++ii) {
            float acc[4];
#pragma unroll
            for (int g = 0; g < 4; ++g) {
                const int rr = ii * 4 + g;
                float s = biasS[rr];
#pragma unroll
                for (int k = 0; k < 8; ++k) {
                    float4 w = WL[rr * 8 + k];
                    s = fmaf(a[k].x, w.x, s);
                    s = fmaf(a[k].y, w.y, s);
                    s = fmaf(a[k].z, w.z, s);
                    s = fmaf(a[k].w, w.w, s);
                }
                acc[g] = s;
            }
            Xp[R * 4 + ii] = make_float4(acc[0], acc[1], acc[2], acc[3]);
        }
    }
    __syncthreads();

    // ---- phase 2: 16-lane recurrence ----
    if (l >= 16) return;                       // exec-masked; latency-bound phase

    const int bl = l >> 2, i = l & 3;
    const int bg = B0 + bl;
    const bool m1 = (i >= 1), m2 = (i >= 2);

    // h-weights: wh*[e] = W_*[i][32+e] / pi  (h_e is in-lane at slot e)
    float whf[4], whi[4], whu[4], who[4];
#pragma unroll
    for (int e = 0; e < 4; ++e) {
        const int col = i * 36 + 32 + e;
        whf[e] = Wf[col] * INV_PI;
        whi[e] = Wi[col] * INV_PI;
        whu[e] = Wu[col] * INV_PI;
        who[e] = Wo[col] * INV_PI;
    }

    // sigmoid(q) on [0,1], deg-3 (Chebyshev-node fit)
    const float S0 = 0.499971f, S1 = 0.250882f, S2 = -0.004115f, S3 = -0.015724f;
    // tanh(q) on [0,1], deg-3
    const float U0 = 0.0008346f, U1 = 1.036967f, U2 = -0.175884f, U3 = -0.099350f;
    // tanh(c) for |c|<=2.08: c*P(c^2), deg-4
    const float T0 = 0.99827f, T1 = -0.313542f, T2 = 0.0915168f,
                T3 = -0.0160296f, T4 = 0.0011677f;

    float h0 = 0.f, h1 = 0.f, h2 = 0.f, h3 = 0.f, cst = 0.f, hlast = 0.f;

    const float4* Xb = Xp + bl * 4 + i;        // step t at +t*16 (float4 units)
    float* outb = out + (size_t)bg * 4 + i;

    // 4-deep LDS->reg prefetch ring
    float4 xr[4];
#pragma unroll
    for (int k = 0; k < 4; ++k) xr[k] = Xb[k * 16];

    for (int t0 = 0; t0 < TSTEPS; t0 += 4) {
#pragma unroll
        for (int k = 0; k < 4; ++k) {
            const int t = t0 + k;
            float4 xp = xr[k];
            int tn = t + 4;  if (tn > TSTEPS - 1) tn = TSTEPS - 1;
            xr[k] = Xb[tn * 16];

            // pre-activations /pi — 4 gates in-lane, balanced trees (ILP 4)
            float Af = fmaf(whf[0], h0, xp.x), Bf = fmaf(whf[1], h1, whf[2] * h2);
            float Ag = fmaf(whi[0], h0, xp.y), Bg = fmaf(whi[1], h1, whi[2] * h2);
            float Au = fmaf(whu[0], h0, xp.z), Bu = fmaf(whu[1], h1, whu[2] * h2);
            float Ao = fmaf(who[0], h0, xp.w), Bo = fmaf(who[1], h1, who[2] * h2);
            float p0 = fmaf(whf[3], h3, Af) + Bf;
            float p1 = fmaf(whi[3], h3, Ag) + Bg;
            float p2 = fmaf(whu[3], h3, Au) + Bu;
            float p3 = fmaf(who[3], h3, Ao) + Bo;

            // cos^2(pre) = 0.5 + 0.5*cos_rev(pre/pi)   (4x ILP)
            float q0 = fmaf(0.5f, __builtin_amdgcn_cosf(__builtin_amdgcn_fractf(p0)), 0.5f);
            float q1 = fmaf(0.5f, __builtin_amdgcn_cosf(__builtin_amdgcn_fractf(p1)), 0.5f);
            float q2 = fmaf(0.5f, __builtin_amdgcn_cosf(__builtin_amdgcn_fractf(p2)), 0.5f);
            float q3 = fmaf(0.5f, __builtin_amdgcn_cosf(__builtin_amdgcn_fractf(p3)), 0.5f);

            // prefix product over i (within quad) — DPP depth 2, 4-gate ILP
            float s0 = qperm<0x90>(q0);  q0 *= m1 ? s0 : 1.0f;
            float s1 = qperm<0x90>(q1);  q1 *= m1 ? s1 : 1.0f;
            float s2 = qperm<0x90>(q2);  q2 *= m1 ? s2 : 1.0f;
            float s3 = qperm<0x90>(q3);  q3 *= m1 ? s3 : 1.0f;
            float u0 = qperm<0x44>(q0);  q0 *= m2 ? u0 : 1.0f;
            float u1 = qperm<0x44>(q1);  q1 *= m2 ? u1 : 1.0f;
            float u2 = qperm<0x44>(q2);  q2 *= m2 ? u2 : 1.0f;
            float u3 = qperm<0x44>(q3);  q3 *= m2 ? u3 : 1.0f;

            // activations in-lane (ILP 4)
            float yf = fmaf(fmaf(fmaf(S3, q0, S2), q0, S1), q0, S0);
            float yi = fmaf(fmaf(fmaf(S3, q1, S2), q1, S1), q1, S0);
            float yu = fmaf(fmaf(fmaf(U3, q2, U2), q2, U1), q2, U0);
            float yo = fmaf(fmaf(fmaf(S3, q3, S2), q3, S1), q3, S0);

            // c and h fully in-lane (c_i owned by lane i)
            cst = fmaf(yf, cst, yi * yu);
            float tt = cst * cst;
            float gg = fmaf(fmaf(fmaf(fmaf(T4, tt, T3), tt, T2), tt, T1), tt, T0);
            float hn = yo * (cst * gg);
            hlast = hn;

            outb[(size_t)t * (NBATCH * 4)] = hn;   // off-chain store

            // h-broadcast within quad: depth-1 DPP, 4x ILP
            h0 = qperm<0x00>(hn);
            h1 = qperm<0x55>(hn);
            h2 = qperm<0xAA>(hn);
            h3 = qperm<0xFF>(hn);
        }
    }

    const size_t off = (size_t)TSTEPS * NBATCH * 4;
    out[off + (size_t)bg * 4 + i] = hlast;                     // final hx
    out[off + (size_t)NBATCH * 4 + (size_t)bg * 4 + i] = cst;  // final cx
}

extern "C" void kernel_launch(void* const* d_in, const int* in_sizes, int n_in,
                              void* d_out, int out_size, void* d_ws, size_t ws_size,
                              hipStream_t stream) {
    (void)in_sizes; (void)n_in; (void)out_size; (void)d_ws; (void)ws_size;
    const float* x  = (const float*)d_in[0];
    const float* Wf = (const float*)d_in[1];
    const float* bf = (const float*)d_in[2];
    // d_in[3] = pf: RZ phases drop out of the measurement -> unused
    const float* Wi = (const float*)d_in[4];
    const float* bi = (const float*)d_in[5];
    const float* Wu = (const float*)d_in[7];
    const float* bu = (const float*)d_in[8];
    const float* Wo = (const float*)d_in[10];
    const float* bo = (const float*)d_in[11];
    float* out = (float*)d_out;

    hipLaunchKernelGGL(qlstm_one, dim3(NBATCH / 4), dim3(64), 0, stream,
                       x, Wf, bf, Wi, bi, Wu, bu, Wo, bo, out);
}

// Round 12
// 52.226 us; speedup vs baseline: 2.5186x; 2.5186x over previous
//
#include <hip/hip_runtime.h>

#define TSTEPS 128
#define NBATCH 2048
#define DIN    32
#define NROWS  (TSTEPS * NBATCH)
#define INV_PI 0.31830988618379067f

// ---- quad-scoped DPP permute (acts within each group of 4 lanes) ----
template <int CTRL>
__device__ __forceinline__ float qperm(float v) {
    return __int_as_float(
        __builtin_amdgcn_mov_dpp(__float_as_int(v), CTRL, 0xF, 0xF, true));
}
// quad_perm ctrl: sel3<<6|sel2<<4|sel1<<2|sel0.
//  0x90 = [0,0,1,2] shift-up-1 ; 0x44 = [0,1,0,1] shift-up-2
//  0x00/0x55/0xAA/0xFF = broadcast quad-lane 0/1/2/3

// ======================= Kernel A: x-projection GEMM =======================
// ws[row*16 + i*4 + g] = (1/pi)*(b_g[i] + x[row,:] . W_g[i,0:32])
// i-major, gate order g: 0=f,1=i,2=u,3=o.  row = t*NBATCH + b.
extern "C" __global__ void __launch_bounds__(256)
xproj_kernel(const float* __restrict__ x,
             const float* __restrict__ Wf, const float* __restrict__ bfp,
             const float* __restrict__ Wi, const float* __restrict__ bip,
             const float* __restrict__ Wu, const float* __restrict__ bup,
             const float* __restrict__ Wo, const float* __restrict__ bop,
             float* __restrict__ ws)
{
    __shared__ float4 WL[16 * 8];
    __shared__ float  bias[16];
    const int tid = threadIdx.x;
    float* WLf = (float*)WL;
    for (int idx = tid; idx < 512; idx += 256) {
        int rr = idx >> 5, k = idx & 31;          // rr = i*4+g
        int i = rr >> 2, g = rr & 3;
        const float* W = (g == 0) ? Wf : (g == 1) ? Wi : (g == 2) ? Wu : Wo;
        WLf[rr * 32 + k] = W[i * 36 + k] * INV_PI;
    }
    if (tid < 16) {
        int i = tid >> 2, g = tid & 3;
        const float* bp = (g == 0) ? bfp : (g == 1) ? bip : (g == 2) ? bup : bop;
        bias[tid] = bp[i] * INV_PI;
    }
    __syncthreads();

    const int row0 = blockIdx.x * 512 + tid;      // 2 rows/thread, stride 256
    const float4* xv = reinterpret_cast<const float4*>(x);
    float4 xa[2][8];
#pragma unroll
    for (int j = 0; j < 2; ++j) {
        int row = row0 + j * 256;
#pragma unroll
        for (int k = 0; k < 8; ++k) xa[j][k] = xv[row * 8 + k];
    }
    float acc[2][16];
#pragma unroll
    for (int rr = 0; rr < 16; ++rr) {
        float4 w[8];
#pragma unroll
        for (int k = 0; k < 8; ++k) w[k] = WL[rr * 8 + k];
#pragma unroll
        for (int j = 0; j < 2; ++j) {
            float s = bias[rr];
#pragma unroll
            for (int k = 0; k < 8; ++k) {
                s = fmaf(xa[j][k].x, w[k].x, s);
                s = fmaf(xa[j][k].y, w[k].y, s);
                s = fmaf(xa[j][k].z, w[k].z, s);
                s = fmaf(xa[j][k].w, w[k].w, s);
            }
            acc[j][rr] = s;
        }
    }
    float4* wsv = reinterpret_cast<float4*>(ws);
#pragma unroll
    for (int j = 0; j < 2; ++j) {
        int row = row0 + j * 256;
#pragma unroll
        for (int ii = 0; ii < 4; ++ii)
            wsv[row * 4 + ii] =
                make_float4(acc[j][ii * 4 + 0], acc[j][ii * 4 + 1],
                            acc[j][ii * 4 + 2], acc[j][ii * 4 + 3]);
    }
}

// ======================= Kernel B: serial recurrence v2 =======================
// 128 blocks x 64 lanes. Quad = one batch (16 batches/block), lane = hidden i.
// ALL 4 gates in-lane (xp = float4 (pf,pi,pu,po) for hidden i); c_i in-lane.
// Cross-lane per step: prefix-product (DPP depth 2) + h-broadcast (depth 1).
// Global loads via 4-deep register ring (coalesced float4; no stores in the
// vmcnt queue); per-step outputs staged in LDS, flushed coalesced at the end.
extern "C" __global__ void __launch_bounds__(64)
recur_kernel(const float* __restrict__ ws,
             const float* __restrict__ Wf, const float* __restrict__ Wi,
             const float* __restrict__ Wu, const float* __restrict__ Wo,
             float* __restrict__ out)
{
    __shared__ float Ols[TSTEPS * 64];            // 32 KB: [t][bl*4+i]

    const int l  = threadIdx.x;
    const int bl = l >> 2, i = l & 3;
    const int B0 = blockIdx.x * 16;
    const int bg = B0 + bl;
    const bool m1 = (i >= 1), m2 = (i >= 2);

    // h-weights: wh*[e] = W_*[i][32+e]/pi  (h_e broadcast from quad lane e)
    float whf[4], whi[4], whu[4], who[4];
#pragma unroll
    for (int e = 0; e < 4; ++e) {
        const int col = i * 36 + 32 + e;
        whf[e] = Wf[col] * INV_PI;
        whi[e] = Wi[col] * INV_PI;
        whu[e] = Wu[col] * INV_PI;
        who[e] = Wo[col] * INV_PI;
    }

    // sigmoid(q) on [0,1], deg-3;  tanh(q) on [0,1], deg-3
    const float S0 = 0.499971f, S1 = 0.250882f, S2 = -0.004115f, S3 = -0.015724f;
    const float U0 = 0.0008346f, U1 = 1.036967f, U2 = -0.175884f, U3 = -0.099350f;
    // tanh(c) for |c|<=2.08: c*P(c^2), deg-4
    const float T0 = 0.99827f, T1 = -0.313542f, T2 = 0.0915168f,
                T3 = -0.0160296f, T4 = 0.0011677f;

    float h0 = 0.f, h1 = 0.f, h2 = 0.f, h3 = 0.f, cst = 0.f, hlast = 0.f;

    const float4* X = reinterpret_cast<const float4*>(ws);
    const int base = B0 * 4 + l;                  // float4 idx in a timestep
    const int TSTR = NBATCH * 4;                  // float4 per timestep

    // 4-deep global->reg prefetch ring (only loads in the vmcnt queue)
    float4 xr[4];
#pragma unroll
    for (int k = 0; k < 4; ++k) xr[k] = X[(size_t)k * TSTR + base];

    for (int t0 = 0; t0 < TSTEPS; t0 += 4) {
#pragma unroll
        for (int k = 0; k < 4; ++k) {
            const int t = t0 + k;
            float4 xp = xr[k];
            int tn = t + 4;  if (tn > TSTEPS - 1) tn = TSTEPS - 1;
            xr[k] = X[(size_t)tn * TSTR + base];

            // pre-activations /pi — 4 gates in-lane, balanced trees (ILP 4)
            float Af = fmaf(whf[0], h0, xp.x), Bf = fmaf(whf[1], h1, whf[2] * h2);
            float Ag = fmaf(whi[0], h0, xp.y), Bg = fmaf(whi[1], h1, whi[2] * h2);
            float Au = fmaf(whu[0], h0, xp.z), Bu = fmaf(whu[1], h1, whu[2] * h2);
            float Ao = fmaf(who[0], h0, xp.w), Bo = fmaf(who[1], h1, who[2] * h2);
            float p0 = fmaf(whf[3], h3, Af) + Bf;
            float p1 = fmaf(whi[3], h3, Ag) + Bg;
            float p2 = fmaf(whu[3], h3, Au) + Bu;
            float p3 = fmaf(who[3], h3, Ao) + Bo;

            // cos^2(pre) = 0.5 + 0.5*cos_rev(pre/pi)  (4x ILP)
            float q0 = fmaf(0.5f, __builtin_amdgcn_cosf(__builtin_amdgcn_fractf(p0)), 0.5f);
            float q1 = fmaf(0.5f, __builtin_amdgcn_cosf(__builtin_amdgcn_fractf(p1)), 0.5f);
            float q2 = fmaf(0.5f, __builtin_amdgcn_cosf(__builtin_amdgcn_fractf(p2)), 0.5f);
            float q3 = fmaf(0.5f, __builtin_amdgcn_cosf(__builtin_amdgcn_fractf(p3)), 0.5f);

            // prefix product over i within quad — DPP depth 2, 4-gate ILP
            float s0 = qperm<0x90>(q0);  q0 *= m1 ? s0 : 1.0f;
            float s1 = qperm<0x90>(q1);  q1 *= m1 ? s1 : 1.0f;
            float s2 = qperm<0x90>(q2);  q2 *= m1 ? s2 : 1.0f;
            float s3 = qperm<0x90>(q3);  q3 *= m1 ? s3 : 1.0f;
            float u0 = qperm<0x44>(q0);  q0 *= m2 ? u0 : 1.0f;
            float u1 = qperm<0x44>(q1);  q1 *= m2 ? u1 : 1.0f;
            float u2 = qperm<0x44>(q2);  q2 *= m2 ? u2 : 1.0f;
            float u3 = qperm<0x44>(q3);  q3 *= m2 ? u3 : 1.0f;

            // activations in-lane (ILP 4)
            float yf = fmaf(fmaf(fmaf(S3, q0, S2), q0, S1), q0, S0);
            float yi = fmaf(fmaf(fmaf(S3, q1, S2), q1, S1), q1, S0);
            float yu = fmaf(fmaf(fmaf(U3, q2, U2), q2, U1), q2, U0);
            float yo = fmaf(fmaf(fmaf(S3, q3, S2), q3, S1), q3, S0);

            // c and h fully in-lane (c_i owned by lane i)
            cst = fmaf(yf, cst, yi * yu);
            float tt = cst * cst;
            float gg = fmaf(fmaf(fmaf(fmaf(T4, tt, T3), tt, T2), tt, T1), tt, T0);
            float hn = yo * (cst * gg);
            hlast = hn;

            Ols[t * 64 + l] = hn;                 // LDS store, off-chain

            // h-broadcast within quad: depth-1 DPP, 4x ILP
            h0 = qperm<0x00>(hn);
            h1 = qperm<0x55>(hn);
            h2 = qperm<0xAA>(hn);
            h3 = qperm<0xFF>(hn);
        }
    }

    __syncthreads();   // single wave: orders LDS for the flush

    // ---- flush: 32 float4 per lane, coalesced ----
    float4* outv = reinterpret_cast<float4*>(out);
    const float4* Ols4 = reinterpret_cast<const float4*>(Ols);
#pragma unroll
    for (int m = 0; m < 32; ++m) {
        int f4 = m * 64 + l;                      // 0..2047
        int t = f4 >> 4, b = f4 & 15;             // b = batch-in-block
        outv[(size_t)t * (NBATCH) + (B0 >> 0) + b] = Ols4[t * 16 + b];
    }

    const size_t off = (size_t)TSTEPS * NBATCH * 4;
    out[off + (size_t)bg * 4 + i] = hlast;                     // final hx
    out[off + (size_t)NBATCH * 4 + (size_t)bg * 4 + i] = cst;  // final cx
}

extern "C" void kernel_launch(void* const* d_in, const int* in_sizes, int n_in,
                              void* d_out, int out_size, void* d_ws, size_t ws_size,
                              hipStream_t stream) {
    (void)in_sizes; (void)n_in; (void)out_size;
    const float* x  = (const float*)d_in[0];
    const float* Wf = (const float*)d_in[1];
    const float* bf = (const float*)d_in[2];
    // d_in[3] = pf: RZ phases drop out of the measurement -> unused
    const float* Wi = (const float*)d_in[4];
    const float* bi = (const float*)d_in[5];
    const float* Wu = (const float*)d_in[7];
    const float* bu = (const float*)d_in[8];
    const float* Wo = (const float*)d_in[10];
    const float* bo = (const float*)d_in[11];
    float* out = (float*)d_out;

    float* ws = (float*)d_ws;   // 16.78 MB needed; harness ws is larger
    hipLaunchKernelGGL(xproj_kernel, dim3(NROWS / 512), dim3(256), 0, stream,
                       x, Wf, bf, Wi, bi, Wu, bu, Wo, bo, ws);
    hipLaunchKernelGGL(recur_kernel, dim3(NBATCH / 16), dim3(64), 0, stream,
                       ws, Wf, Wi, Wu, Wo, out);
}